// Round 2
// baseline (473.453 us; speedup 1.0000x reference)
//
#include <hip/hip_runtime.h>
#include <cstdint>
#include <cstddef>

// VectorQuantizer: x (16,128,4096) f32, W (1024,128) f32
// out = [quantized_st 8388608 | indices 65536 (as float) | loss 1]
//
// R2: replicate the numpy FLOAT32 reference bit-exactly.
//  - a_r, b_k via numpy pairwise-sum (8-accumulator, n=128) of pre-rounded
//    squares (asm barrier prevents fp-contract fusing the mul into the add)
//  - c_rk via strict sequential-FMA chain over d=0..127 (BLAS sgemm order)
//  - dist = fl(fl(a+b) - 2c); argmin ascending, strict < (first occurrence)

#define BB 16
#define DD 128
#define TT 4096
#define KK 1024
#define NROW 65536
#define QSIZE 8388608
#define IDX_BASE QSIZE
#define LOSS_IDX (QSIZE + NROW)
#define COMMIT 0.25f
#define TPB 256
#define RPB 128           // rows per block (2 threads per row)
#define TC 32             // codes per half-tile
#define NT 16             // tiles per half (16*32 = 512 codes per half)

// optimization barrier: keep value as-is, block fp contraction across it
__device__ __forceinline__ float fb(float v) {
    asm volatile("" : "+v"(v));
    return v;
}

// Kernel 1: b_k = numpy-pairwise sum of fl(W[k][d]^2); zero the loss slot.
__global__ void vq_prep(const float* __restrict__ W, float* __restrict__ wsq,
                        float* __restrict__ d_out) {
    int k = blockIdx.x * blockDim.x + threadIdx.x;
    if (k == 0 && blockIdx.x == 0) d_out[LOSS_IDX] = 0.f;
    if (k < KK) {
        const float* Wr = W + (size_t)k * DD;
        float rr[8];
        #pragma unroll
        for (int j = 0; j < 8; ++j) {
            float w = Wr[j];
            float pp = w * w;
            pp = fb(pp);
            rr[j] = pp;
        }
        #pragma unroll
        for (int i = 8; i <= 120; i += 8) {
            #pragma unroll
            for (int j = 0; j < 8; ++j) {
                float w = Wr[i + j];
                float pp = w * w;
                pp = fb(pp);
                rr[j] += pp;
            }
        }
        wsq[k] = ((rr[0] + rr[1]) + (rr[2] + rr[3])) + ((rr[4] + rr[5]) + (rr[6] + rr[7]));
    }
}

__global__ __launch_bounds__(TPB, 2)
void vq_main(const float* __restrict__ x, const float* __restrict__ W,
             const float* __restrict__ wsq, float* __restrict__ d_out) {
    const int tid   = threadIdx.x;
    const int row_l = tid & (RPB - 1);
    const int h = __builtin_amdgcn_readfirstlane(tid >> 7);   // wave-uniform half id
    const int r = blockIdx.x * RPB + row_l;
    const int b = r >> 12;                 // T = 4096
    const int t = r & (TT - 1);
    const float* xb = x + (size_t)b * DD * TT + t;

    __shared__ float wb[2][TC][DD];        // 32 KB: per-half code tiles
    __shared__ float bbuf[KK];             // 4 KB: ||w||^2
    __shared__ float ms[RPB];
    __shared__ int   mk[RPB];
    __shared__ int   fk[RPB];

    // x row -> 128 VGPRs (coalesced: consecutive t across lanes)
    float xr[DD];
    #pragma unroll
    for (int d = 0; d < DD; ++d) xr[d] = xb[(size_t)d * TT];

    // a_r: numpy pairwise of fl(x_d^2)
    float rr[8];
    #pragma unroll
    for (int j = 0; j < 8; ++j) {
        float pp = xr[j] * xr[j];
        pp = fb(pp);
        rr[j] = pp;
    }
    #pragma unroll
    for (int i = 8; i <= 120; i += 8) {
        #pragma unroll
        for (int j = 0; j < 8; ++j) {
            float pp = xr[i + j] * xr[i + j];
            pp = fb(pp);
            rr[j] += pp;
        }
    }
    const float a = ((rr[0] + rr[1]) + (rr[2] + rr[3])) + ((rr[4] + rr[5]) + (rr[6] + rr[7]));

    // stage ||w||^2 into LDS
    #pragma unroll
    for (int s = 0; s < 4; ++s) bbuf[tid + TPB * s] = wsq[tid + TPB * s];

    const float4* Wv = (const float4*)W;
    float4* wbv = (float4*)wb;

    // prefetch tile-pair 0
    float4 pre[8];
    #pragma unroll
    for (int s = 0; s < 8; ++s) {
        int q    = s * TPB + tid;          // 0..2047
        int half = q >> 10;
        int q1   = q & 1023;
        pre[s] = Wv[half * 16384 + 0 * 1024 + q1];
    }

    float best = 3.4e38f;
    int bk = 0;
    const float* wbase = &wb[h][0][0];

    for (int tt = 0; tt < NT; ++tt) {
        // write staged tile-pair to LDS
        #pragma unroll
        for (int s = 0; s < 8; ++s) wbv[s * TPB + tid] = pre[s];
        __syncthreads();
        // prefetch next tile-pair (overlaps compute)
        if (tt + 1 < NT) {
            #pragma unroll
            for (int s = 0; s < 8; ++s) {
                int q    = s * TPB + tid;
                int half = q >> 10;
                int q1   = q & 1023;
                pre[s] = Wv[half * 16384 + (tt + 1) * 1024 + q1];
            }
        }
        // compute: this half's 32 codes, groups of 4 interleaved seq-FMA chains
        for (int g = 0; g < 8; ++g) {
            const float4* w0 = (const float4*)(wbase + (g * 4 + 0) * DD);
            const float4* w1 = (const float4*)(wbase + (g * 4 + 1) * DD);
            const float4* w2 = (const float4*)(wbase + (g * 4 + 2) * DD);
            const float4* w3 = (const float4*)(wbase + (g * 4 + 3) * DD);
            float ac0 = 0.f, ac1 = 0.f, ac2 = 0.f, ac3 = 0.f;
            #pragma unroll
            for (int dq = 0; dq < 32; ++dq) {
                float4 a0 = w0[dq], a1 = w1[dq], a2 = w2[dq], a3 = w3[dq];
                float x0 = xr[dq * 4 + 0], x1 = xr[dq * 4 + 1];
                float x2 = xr[dq * 4 + 2], x3 = xr[dq * 4 + 3];
                ac0 = __builtin_fmaf(x0, a0.x, ac0); ac0 = __builtin_fmaf(x1, a0.y, ac0);
                ac0 = __builtin_fmaf(x2, a0.z, ac0); ac0 = __builtin_fmaf(x3, a0.w, ac0);
                ac1 = __builtin_fmaf(x0, a1.x, ac1); ac1 = __builtin_fmaf(x1, a1.y, ac1);
                ac1 = __builtin_fmaf(x2, a1.z, ac1); ac1 = __builtin_fmaf(x3, a1.w, ac1);
                ac2 = __builtin_fmaf(x0, a2.x, ac2); ac2 = __builtin_fmaf(x1, a2.y, ac2);
                ac2 = __builtin_fmaf(x2, a2.z, ac2); ac2 = __builtin_fmaf(x3, a2.w, ac2);
                ac3 = __builtin_fmaf(x0, a3.x, ac3); ac3 = __builtin_fmaf(x1, a3.y, ac3);
                ac3 = __builtin_fmaf(x2, a3.z, ac3); ac3 = __builtin_fmaf(x3, a3.w, ac3);
            }
            const int cbase = h * 512 + tt * TC + g * 4;
            // ascending code order, strict < => numpy first-occurrence argmin
            {
                float tw = ac0 + ac0; float t1 = a + bbuf[cbase + 0];
                float dist = t1 - tw;
                if (dist < best) { best = dist; bk = cbase + 0; }
            }
            {
                float tw = ac1 + ac1; float t1 = a + bbuf[cbase + 1];
                float dist = t1 - tw;
                if (dist < best) { best = dist; bk = cbase + 1; }
            }
            {
                float tw = ac2 + ac2; float t1 = a + bbuf[cbase + 2];
                float dist = t1 - tw;
                if (dist < best) { best = dist; bk = cbase + 2; }
            }
            {
                float tw = ac3 + ac3; float t1 = a + bbuf[cbase + 3];
                float dist = t1 - tw;
                if (dist < best) { best = dist; bk = cbase + 3; }
            }
        }
        __syncthreads();
    }

    // merge halves: h0 covers codes 0..511 (wins ties -> first occurrence)
    if (h == 1) { ms[row_l] = best; mk[row_l] = bk; }
    __syncthreads();
    if (h == 0) {
        int kf = (ms[row_l] < best) ? mk[row_l] : bk;
        fk[row_l] = kf;
        d_out[IDX_BASE + r] = (float)kf;
    }
    __syncthreads();
    const int kf = fk[row_l];

    // epilogue: quantized_st = fl(x + fl(q - x)); loss partial
    const float* Wk = W + (size_t)kf * DD;
    float* outq = d_out + (size_t)b * DD * TT + t;
    float acc = 0.f;
    if (h == 0) {
        const float4* Wk4 = (const float4*)Wk;
        #pragma unroll
        for (int dq = 0; dq < 16; ++dq) {
            float4 q4 = Wk4[dq];
            int d0 = dq * 4;
            { float xv = xr[d0 + 0]; float dlt = q4.x - xv; outq[(size_t)(d0 + 0) * TT] = xv + dlt; acc = fmaf(dlt, dlt, acc); }
            { float xv = xr[d0 + 1]; float dlt = q4.y - xv; outq[(size_t)(d0 + 1) * TT] = xv + dlt; acc = fmaf(dlt, dlt, acc); }
            { float xv = xr[d0 + 2]; float dlt = q4.z - xv; outq[(size_t)(d0 + 2) * TT] = xv + dlt; acc = fmaf(dlt, dlt, acc); }
            { float xv = xr[d0 + 3]; float dlt = q4.w - xv; outq[(size_t)(d0 + 3) * TT] = xv + dlt; acc = fmaf(dlt, dlt, acc); }
        }
    } else {
        const float4* Wk4 = (const float4*)Wk + 16;
        #pragma unroll
        for (int dq = 0; dq < 16; ++dq) {
            float4 q4 = Wk4[dq];
            int d0 = 64 + dq * 4;
            { float xv = xr[d0 + 0]; float dlt = q4.x - xv; outq[(size_t)(d0 + 0) * TT] = xv + dlt; acc = fmaf(dlt, dlt, acc); }
            { float xv = xr[d0 + 1]; float dlt = q4.y - xv; outq[(size_t)(d0 + 1) * TT] = xv + dlt; acc = fmaf(dlt, dlt, acc); }
            { float xv = xr[d0 + 2]; float dlt = q4.z - xv; outq[(size_t)(d0 + 2) * TT] = xv + dlt; acc = fmaf(dlt, dlt, acc); }
            { float xv = xr[d0 + 3]; float dlt = q4.w - xv; outq[(size_t)(d0 + 3) * TT] = xv + dlt; acc = fmaf(dlt, dlt, acc); }
        }
    }

    // block-reduce loss partial -> one atomic per block
    #pragma unroll
    for (int off = 32; off > 0; off >>= 1) acc += __shfl_down(acc, off, 64);
    __shared__ float wred[4];
    const int wid = tid >> 6;
    if ((tid & 63) == 0) wred[wid] = acc;
    __syncthreads();
    if (tid == 0) {
        float ssum = (wred[0] + wred[1]) + (wred[2] + wred[3]);
        atomicAdd(&d_out[LOSS_IDX], ssum * (COMMIT / (float)QSIZE));
    }
}

extern "C" void kernel_launch(void* const* d_in, const int* in_sizes, int n_in,
                              void* d_out, int out_size, void* d_ws, size_t ws_size,
                              hipStream_t stream) {
    const float* x = (const float*)d_in[0];
    const float* W = (const float*)d_in[1];
    float* out = (float*)d_out;
    float* wsq = (float*)d_ws;   // 1024 floats of scratch

    vq_prep<<<4, 256, 0, stream>>>(W, wsq, out);
    vq_main<<<NROW / RPB, TPB, 0, stream>>>(x, W, wsq, out);
}